// Round 4
// baseline (316.041 us; speedup 1.0000x reference)
//
#include <hip/hip_runtime.h>
#include <stdint.h>

typedef unsigned int u32;
typedef short short8 __attribute__((ext_vector_type(8)));
typedef short bf16x8 __attribute__((ext_vector_type(8)));
typedef float f32x4  __attribute__((ext_vector_type(4)));

#define B_ROWS 8192
#define HID    1024
#define KDIM   3072
#define NGATE  5

// GEMM tile: 256 batch rows x (5 gates x 64 hidden) per block, 8 waves 2Mx4N,
// per-wave output 128x80 (8 M-frags x 5 N-frags; N-frag == gate index).
#define BM 256
#define BN 320
#define BK 64
#define NT (KDIM / BK)
#define LDSA_SH (BM * BK)            // 16384 shorts
#define LDSB_SH (BN * BK)            // 20480 shorts
#define BUF_SH  (LDSA_SH + LDSB_SH)  // 36864 shorts = 72 KiB
#define BUF_BYTES (BUF_SH * 2)       // 73728

// ---------- helpers ----------
__device__ __forceinline__ short f2bf(float f) {
  u32 u = __builtin_bit_cast(u32, f);
  u += 0x7FFFu + ((u >> 16) & 1u);   // round-to-nearest-even
  return (short)(u >> 16);
}

__device__ __forceinline__ float sigf(float v) { return 1.0f / (1.0f + __expf(-v)); }

__device__ __forceinline__ void async_copy16(const void* g, void* l) {
  __builtin_amdgcn_global_load_lds(
      (__attribute__((address_space(1))) void*)(g),
      (__attribute__((address_space(3))) void*)(l),
      16, 0, 0);
}

// ---------- conversion kernels ----------
__global__ void convert_combined(const float* __restrict__ x,
                                 const float* __restrict__ hl,
                                 const float* __restrict__ hr,
                                 short* __restrict__ out) {
  const int total  = B_ROWS * (KDIM / 8);
  const int stride = gridDim.x * blockDim.x;
  for (int i = blockIdx.x * blockDim.x + threadIdx.x; i < total; i += stride) {
    int row = i / (KDIM / 8);
    int col = (i - row * (KDIM / 8)) * 8;
    const float* src;
    if (col < 1024)      src = x  + (int64_t)row * 1024 + col;
    else if (col < 2048) src = hl + (int64_t)row * 1024 + (col - 1024);
    else                 src = hr + (int64_t)row * 1024 + (col - 2048);
    float4 v0 = ((const float4*)src)[0];
    float4 v1 = ((const float4*)src)[1];
    short8 r;
    r[0] = f2bf(v0.x); r[1] = f2bf(v0.y); r[2] = f2bf(v0.z); r[3] = f2bf(v0.w);
    r[4] = f2bf(v1.x); r[5] = f2bf(v1.y); r[6] = f2bf(v1.z); r[7] = f2bf(v1.w);
    *(short8*)(out + (int64_t)row * KDIM + col) = r;
  }
}

__global__ void convert_w(const float* __restrict__ Wf, short* __restrict__ out) {
  const int total  = NGATE * HID * (KDIM / 8);
  const int stride = gridDim.x * blockDim.x;
  for (int i = blockIdx.x * blockDim.x + threadIdx.x; i < total; i += stride) {
    int64_t e = (int64_t)i * 8;
    float4 v0 = ((const float4*)(Wf + e))[0];
    float4 v1 = ((const float4*)(Wf + e))[1];
    short8 r;
    r[0] = f2bf(v0.x); r[1] = f2bf(v0.y); r[2] = f2bf(v0.z); r[3] = f2bf(v0.w);
    r[4] = f2bf(v1.x); r[5] = f2bf(v1.y); r[6] = f2bf(v1.z); r[7] = f2bf(v1.w);
    *(short8*)(out + e) = r;
  }
}

// ---------- fused GEMM + LSTM-cell epilogue ----------
// Counted-vmcnt deep pipeline (T3+T4): tile t+2's loads stream into tile t's
// OWN buffer as regions die (B dead after p0's barrier; A slice p dead after
// phase p's barrier -> wave w issues its A-loads at phase w&3). Every wave
// issues 9 loads/tile, so tile-end wait = vmcnt(9) (t+1's loads are the
// oldest 9; vmcnt completes in order). Never drains to 0 until the tail.
__global__ __launch_bounds__(512, 2) void lstm_gemm(
    const short* __restrict__ Abf,   // [8192][3072] bf16
    const short* __restrict__ Wbf,   // [5120][3072] bf16
    const float* __restrict__ bias,  // [5120]
    const float* __restrict__ c_left,
    const float* __restrict__ c_right,
    float* __restrict__ out) {       // h at 0, c at 8192*1024
  __shared__ short lds[2 * BUF_SH];  // 144 KiB
  char* const ldsc = (char*)lds;

  const int tid = threadIdx.x;
  const int w  = tid >> 6;     // 0..7
  const int l  = tid & 63;
  const int wm = w >> 2;       // 0..1
  const int wn = w & 3;        // 0..3
  const int wphase = w & 3;    // phase at which this wave's A-region dies
  const int lc = l & 15;
  const int khalf = l >> 4;    // 0..3

  // XCD-aware bijective swizzle (512 % 8 == 0)
  const int bid = blockIdx.x;
  const int wg  = (bid & 7) * 64 + (bid >> 3);
  const int m0  = (wg >> 4) * BM;
  const int j0  = (wg & 15) * 64;

  // staging: per wave-load 8 rows x 128B; lane l -> row += l>>3, slot l&7
  const int r8 = l >> 3;
  const int sl = (l & 7) ^ r8;      // pre-swizzled source slot
  u32 aoff[4], boff[5];
#pragma unroll
  for (int i = 0; i < 4; ++i)
    aoff[i] = (u32)(m0 + (w * 4 + i) * 8 + r8) * KDIM + sl * 8;
#pragma unroll
  for (int i = 0; i < 5; ++i) {
    int rb = (w * 5 + i) * 8 + r8;                 // 0..319
    int g  = (rb % 80) >> 4;
    int dj = (rb / 80) * 16 + (rb & 15);
    boff[i] = (u32)(g * HID + j0 + dj) * KDIM + sl * 8;
  }

  // ds_read byte addresses (buffer 0); row&7 == lc&7 since rows are 16k+lc
  const u32 sw0 = (u32)(((khalf    ) ^ (lc & 7)) * 16);
  const u32 sw1 = (u32)(((khalf + 4) ^ (lc & 7)) * 16);
  u32 aAd0 = (u32)((wm * 128 + lc) * 128) + sw0;
  u32 aAd1 = (u32)((wm * 128 + lc) * 128) + sw1;
  u32 bAd0 = (u32)(LDSA_SH * 2) + (u32)((wn * 80 + lc) * 128) + sw0;
  u32 bAd1 = (u32)(LDSA_SH * 2) + (u32)((wn * 80 + lc) * 128) + sw1;

  f32x4 acc[8][5];
  const f32x4 zero = {0.0f, 0.0f, 0.0f, 0.0f};
#pragma unroll
  for (int m = 0; m < 8; ++m)
#pragma unroll
    for (int n = 0; n < 5; ++n) acc[m][n] = zero;

  // ---- prologue: stage tiles 0 and 1; wait only for tile 0 ----
#pragma unroll
  for (int i = 0; i < 4; ++i)
    async_copy16(Abf + aoff[i], lds + (w * 4 + i) * 512);
#pragma unroll
  for (int i = 0; i < 5; ++i)
    async_copy16(Wbf + boff[i], lds + LDSA_SH + (w * 5 + i) * 512);
#pragma unroll
  for (int i = 0; i < 4; ++i) aoff[i] += BK;
#pragma unroll
  for (int i = 0; i < 5; ++i) boff[i] += BK;
#pragma unroll
  for (int i = 0; i < 4; ++i)
    async_copy16(Abf + aoff[i], lds + BUF_SH + (w * 4 + i) * 512);
#pragma unroll
  for (int i = 0; i < 5; ++i)
    async_copy16(Wbf + boff[i], lds + BUF_SH + LDSA_SH + (w * 5 + i) * 512);
#pragma unroll
  for (int i = 0; i < 4; ++i) aoff[i] += BK;
#pragma unroll
  for (int i = 0; i < 5; ++i) boff[i] += BK;
  asm volatile("s_waitcnt vmcnt(9)" ::: "memory");  // tile 0 landed; tile 1 in flight
  __builtin_amdgcn_s_barrier();

  int bufd = BUF_BYTES;
  for (int t = 0; t < NT; ++t) {
    short* const dstA = lds + (t & 1) * BUF_SH;   // t+2 shares tile t's buffer
    short* const dstB = dstA + LDSA_SH;
    const bool pre = (t < NT - 2);
    bf16x8 bfr[5][2];

#pragma unroll
    for (int p = 0; p < 4; ++p) {
      if (p == 0) {
        // read all B-frags once; held in regs for the whole K-tile
#pragma unroll
        for (int nf = 0; nf < 5; ++nf) {
          bfr[nf][0] = *(const bf16x8*)(ldsc + bAd0 + nf * 2048);
          bfr[nf][1] = *(const bf16x8*)(ldsc + bAd1 + nf * 2048);
        }
      }
      bf16x8 af[2][2];
#pragma unroll
      for (int mf = 0; mf < 2; ++mf) {
        af[mf][0] = *(const bf16x8*)(ldsc + aAd0 + (p * 32 + mf * 16) * 128);
        af[mf][1] = *(const bf16x8*)(ldsc + aAd1 + (p * 32 + mf * 16) * 128);
      }
      __builtin_amdgcn_s_barrier();
      __builtin_amdgcn_sched_barrier(0);  // pin issues below the freeing barrier
      if (pre) {
        if (p == 0) {  // B(t) dead for all waves -> stream B(t+2) in
#pragma unroll
          for (int i = 0; i < 5; ++i)
            async_copy16(Wbf + boff[i], dstB + (w * 5 + i) * 512);
        }
        if (wphase == p) {  // this wave's A(t) rows dead -> stream A(t+2) in
#pragma unroll
          for (int i = 0; i < 4; ++i)
            async_copy16(Abf + aoff[i], dstA + (w * 4 + i) * 512);
        }
      }
      __builtin_amdgcn_s_setprio(1);
#pragma unroll
      for (int mf = 0; mf < 2; ++mf)
#pragma unroll
        for (int nf = 0; nf < 5; ++nf)
#pragma unroll
          for (int kk = 0; kk < 2; ++kk)
            acc[p * 2 + mf][nf] = __builtin_amdgcn_mfma_f32_16x16x32_bf16(
                af[mf][kk], bfr[nf][kk], acc[p * 2 + mf][nf], 0, 0, 0);
      __builtin_amdgcn_s_setprio(0);
      if (p == 3) {
        // counted wait: oldest 9 = tile t+1's loads (issued during t-1)
        if (t < NT - 2)       asm volatile("s_waitcnt vmcnt(9)" ::: "memory");
        else if (t == NT - 2) asm volatile("s_waitcnt vmcnt(0)" ::: "memory");
      }
      __builtin_amdgcn_s_barrier();
    }
    aAd0 += bufd; aAd1 += bufd; bAd0 += bufd; bAd1 += bufd;
    bufd = -bufd;
    if (pre) {
#pragma unroll
      for (int i = 0; i < 4; ++i) aoff[i] += BK;
#pragma unroll
      for (int i = 0; i < 5; ++i) boff[i] += BK;
    }
  }

  // ---- epilogue: 5 gates for (row, j) all live in this lane ----
  const int j = j0 + wn * 16 + lc;
  float bi[5];
#pragma unroll
  for (int g = 0; g < 5; ++g) bi[g] = bias[g * HID + j];
#pragma unroll
  for (int m = 0; m < 8; ++m) {
#pragma unroll
    for (int r = 0; r < 4; ++r) {
      const int row = m0 + wm * 128 + m * 16 + khalf * 4 + r;
      const int off = row * HID + j;
      float iv  = sigf(acc[m][0][r] + bi[0]);
      float flv = sigf(acc[m][1][r] + bi[1]);
      float frv = sigf(acc[m][2][r] + bi[2]);
      float ov  = sigf(acc[m][3][r] + bi[3]);
      float uv  = tanhf(acc[m][4][r] + bi[4]);
      float cv  = iv * uv + flv * c_left[off] + frv * c_right[off];
      out[off] = ov * tanhf(cv);
      out[B_ROWS * HID + off] = cv;
    }
  }
}

// ---------- fp32 fallback (only if ws too small) ----------
__global__ void lstm_fallback(const float* __restrict__ x, const float* __restrict__ hl,
                              const float* __restrict__ hr, const float* __restrict__ cl,
                              const float* __restrict__ cr, const float* __restrict__ W,
                              const float* __restrict__ b, float* __restrict__ out) {
  int64_t idx = (int64_t)blockIdx.x * blockDim.x + threadIdx.x;
  if (idx >= (int64_t)B_ROWS * HID) return;
  int bi = (int)(idx >> 10);
  int j  = (int)(idx & 1023);
  float acc[5];
#pragma unroll
  for (int g = 0; g < 5; ++g) acc[g] = b[g * HID + j];
  const float* segs[3] = {x + (int64_t)bi * 1024, hl + (int64_t)bi * 1024,
                          hr + (int64_t)bi * 1024};
  for (int s = 0; s < 3; ++s) {
    const float4* v = (const float4*)segs[s];
    for (int k4 = 0; k4 < 256; ++k4) {
      float4 a = v[k4];
#pragma unroll
      for (int g = 0; g < 5; ++g) {
        const float4 wv = *(const float4*)(W + (int64_t)(g * HID + j) * KDIM + s * 1024 + k4 * 4);
        acc[g] += a.x * wv.x + a.y * wv.y + a.z * wv.z + a.w * wv.w;
      }
    }
  }
  float iv = sigf(acc[0]), fl = sigf(acc[1]), fr = sigf(acc[2]), ov = sigf(acc[3]);
  float uv = tanhf(acc[4]);
  float cv = iv * uv + fl * cl[idx] + fr * cr[idx];
  out[idx] = ov * tanhf(cv);
  out[(int64_t)B_ROWS * HID + idx] = cv;
}

// ---------- host ----------
extern "C" void kernel_launch(void* const* d_in, const int* in_sizes, int n_in,
                              void* d_out, int out_size, void* d_ws, size_t ws_size,
                              hipStream_t stream) {
  const float* x  = (const float*)d_in[0];
  const float* hl = (const float*)d_in[1];
  const float* cl = (const float*)d_in[2];
  const float* hr = (const float*)d_in[3];
  const float* cr = (const float*)d_in[4];
  const float* W  = (const float*)d_in[5];
  const float* b  = (const float*)d_in[6];
  float* out = (float*)d_out;

  const size_t needA = (size_t)B_ROWS * KDIM * sizeof(short);      // 48 MiB
  const size_t needW = (size_t)NGATE * HID * KDIM * sizeof(short); // 30 MiB

  if (ws_size >= needA + needW) {
    short* Abf = (short*)d_ws;
    short* Wbf = (short*)((char*)d_ws + needA);
    convert_combined<<<2048, 256, 0, stream>>>(x, hl, hr, Abf);
    convert_w<<<2048, 256, 0, stream>>>(W, Wbf);
    lstm_gemm<<<512, 512, 0, stream>>>(Abf, Wbf, b, cl, cr, out);
  } else {
    lstm_fallback<<<(B_ROWS * HID) / 256, 256, 0, stream>>>(x, hl, hr, cl, cr, W, b, out);
  }
}

// Round 5
// 291.478 us; speedup vs baseline: 1.0843x; 1.0843x over previous
//
#include <hip/hip_runtime.h>
#include <stdint.h>

typedef unsigned int u32;
typedef short short8 __attribute__((ext_vector_type(8)));
typedef short bf16x8 __attribute__((ext_vector_type(8)));
typedef float f32x4  __attribute__((ext_vector_type(4)));

#define B_ROWS 8192
#define HID    1024
#define KDIM   3072
#define NGATE  5

// GEMM tile: 256 batch rows x (5 gates x 64 hidden) per block, 8 waves 2Mx4N,
// per-wave output 128x80 (8 M-frags x 5 N-frags; N-frag == gate index).
#define BM 256
#define BN 320
#define BK 64
#define NT (KDIM / BK)
#define LDSA_SH (BM * BK)            // 16384 shorts
#define LDSB_SH (BN * BK)            // 20480 shorts
#define BUF_SH  (LDSA_SH + LDSB_SH)  // 36864 shorts = 72 KiB
#define BUF_BYTES (BUF_SH * 2)       // 73728

// ---------- helpers ----------
__device__ __forceinline__ short f2bf(float f) {
  u32 u = __builtin_bit_cast(u32, f);
  u += 0x7FFFu + ((u >> 16) & 1u);   // round-to-nearest-even
  return (short)(u >> 16);
}

__device__ __forceinline__ float sigf(float v) { return 1.0f / (1.0f + __expf(-v)); }

__device__ __forceinline__ void async_copy16(const void* g, void* l) {
  __builtin_amdgcn_global_load_lds(
      (__attribute__((address_space(1))) void*)(g),
      (__attribute__((address_space(3))) void*)(l),
      16, 0, 0);
}

// ---------- conversion kernels ----------
__global__ void convert_combined(const float* __restrict__ x,
                                 const float* __restrict__ hl,
                                 const float* __restrict__ hr,
                                 short* __restrict__ out) {
  const int total  = B_ROWS * (KDIM / 8);
  const int stride = gridDim.x * blockDim.x;
  for (int i = blockIdx.x * blockDim.x + threadIdx.x; i < total; i += stride) {
    int row = i / (KDIM / 8);
    int col = (i - row * (KDIM / 8)) * 8;
    const float* src;
    if (col < 1024)      src = x  + (int64_t)row * 1024 + col;
    else if (col < 2048) src = hl + (int64_t)row * 1024 + (col - 1024);
    else                 src = hr + (int64_t)row * 1024 + (col - 2048);
    float4 v0 = ((const float4*)src)[0];
    float4 v1 = ((const float4*)src)[1];
    short8 r;
    r[0] = f2bf(v0.x); r[1] = f2bf(v0.y); r[2] = f2bf(v0.z); r[3] = f2bf(v0.w);
    r[4] = f2bf(v1.x); r[5] = f2bf(v1.y); r[6] = f2bf(v1.z); r[7] = f2bf(v1.w);
    *(short8*)(out + (int64_t)row * KDIM + col) = r;
  }
}

__global__ void convert_w(const float* __restrict__ Wf, short* __restrict__ out) {
  const int total  = NGATE * HID * (KDIM / 8);
  const int stride = gridDim.x * blockDim.x;
  for (int i = blockIdx.x * blockDim.x + threadIdx.x; i < total; i += stride) {
    int64_t e = (int64_t)i * 8;
    float4 v0 = ((const float4*)(Wf + e))[0];
    float4 v1 = ((const float4*)(Wf + e))[1];
    short8 r;
    r[0] = f2bf(v0.x); r[1] = f2bf(v0.y); r[2] = f2bf(v0.z); r[3] = f2bf(v0.w);
    r[4] = f2bf(v1.x); r[5] = f2bf(v1.y); r[6] = f2bf(v1.z); r[7] = f2bf(v1.w);
    *(short8*)(out + e) = r;
  }
}

// ---------- fused GEMM + LSTM-cell epilogue ----------
// Drift-pipelined tile loop: ONE barrier per K-tile (write-after-read guard at
// the double-buffer swap), preceded by vmcnt(0)+lgkmcnt(0). No intra-tile
// barriers: all phases only READ the current buffer while staging writes the
// other one, so waves drift and one wave's lgkm stall hides under its
// SIMD-sibling's MFMA. setprio(1) wraps each MFMA cluster (waves now at
// different phases -> scheduler has a role-split to arbitrate, T5).
__global__ __launch_bounds__(512, 2) void lstm_gemm(
    const short* __restrict__ Abf,   // [8192][3072] bf16
    const short* __restrict__ Wbf,   // [5120][3072] bf16
    const float* __restrict__ bias,  // [5120]
    const float* __restrict__ c_left,
    const float* __restrict__ c_right,
    float* __restrict__ out) {       // h at 0, c at 8192*1024
  __shared__ short lds[2 * BUF_SH];  // 144 KiB
  char* const ldsc = (char*)lds;

  const int tid = threadIdx.x;
  const int w  = tid >> 6;     // 0..7
  const int l  = tid & 63;
  const int wm = w >> 2;       // 0..1
  const int wn = w & 3;        // 0..3
  const int lc = l & 15;
  const int khalf = l >> 4;    // 0..3

  // XCD-aware bijective swizzle (512 % 8 == 0)
  const int bid = blockIdx.x;
  const int wg  = (bid & 7) * 64 + (bid >> 3);
  const int m0  = (wg >> 4) * BM;
  const int j0  = (wg & 15) * 64;

  // staging: per wave-load 8 rows x 128B; lane l -> row += l>>3, slot l&7
  const int r8 = l >> 3;
  const int sl = (l & 7) ^ r8;      // pre-swizzled source slot
  u32 aoff[4], boff[5];
#pragma unroll
  for (int i = 0; i < 4; ++i)
    aoff[i] = (u32)(m0 + (w * 4 + i) * 8 + r8) * KDIM + sl * 8;
#pragma unroll
  for (int i = 0; i < 5; ++i) {
    int rb = (w * 5 + i) * 8 + r8;                 // 0..319
    int g  = (rb % 80) >> 4;
    int dj = (rb / 80) * 16 + (rb & 15);
    boff[i] = (u32)(g * HID + j0 + dj) * KDIM + sl * 8;
  }

  // ds_read byte addresses (buffer 0); row&7 == lc&7 since rows are 16k+lc
  const u32 sw0 = (u32)(((khalf    ) ^ (lc & 7)) * 16);
  const u32 sw1 = (u32)(((khalf + 4) ^ (lc & 7)) * 16);
  u32 aAd0 = (u32)((wm * 128 + lc) * 128) + sw0;
  u32 aAd1 = (u32)((wm * 128 + lc) * 128) + sw1;
  u32 bAd0 = (u32)(LDSA_SH * 2) + (u32)((wn * 80 + lc) * 128) + sw0;
  u32 bAd1 = (u32)(LDSA_SH * 2) + (u32)((wn * 80 + lc) * 128) + sw1;

  f32x4 acc[8][5];
  const f32x4 zero = {0.0f, 0.0f, 0.0f, 0.0f};
#pragma unroll
  for (int m = 0; m < 8; ++m)
#pragma unroll
    for (int n = 0; n < 5; ++n) acc[m][n] = zero;

  // ---- prologue: stage tile 0 into buffer 0 ----
#pragma unroll
  for (int i = 0; i < 4; ++i)
    async_copy16(Abf + aoff[i], lds + (w * 4 + i) * 512);
#pragma unroll
  for (int i = 0; i < 5; ++i)
    async_copy16(Wbf + boff[i], lds + LDSA_SH + (w * 5 + i) * 512);
#pragma unroll
  for (int i = 0; i < 4; ++i) aoff[i] += BK;
#pragma unroll
  for (int i = 0; i < 5; ++i) boff[i] += BK;
  asm volatile("s_waitcnt vmcnt(0)" ::: "memory");
  __builtin_amdgcn_s_barrier();

  int bufd = BUF_BYTES;
  for (int t = 0; t < NT; ++t) {
    // ---- stage t+1 into the other buffer (its readers retired at the
    //      barrier that ended tile t-1) ----
    if (t < NT - 1) {
      short* dA = lds + ((t + 1) & 1) * BUF_SH;
      short* dB = dA + LDSA_SH;
#pragma unroll
      for (int i = 0; i < 4; ++i)
        async_copy16(Abf + aoff[i], dA + (w * 4 + i) * 512);
#pragma unroll
      for (int i = 0; i < 5; ++i)
        async_copy16(Wbf + boff[i], dB + (w * 5 + i) * 512);
#pragma unroll
      for (int i = 0; i < 4; ++i) aoff[i] += BK;
#pragma unroll
      for (int i = 0; i < 5; ++i) boff[i] += BK;
    }

    // ---- read all B-frags once; held in regs for the whole K-tile ----
    bf16x8 bfr[5][2];
#pragma unroll
    for (int nf = 0; nf < 5; ++nf) {
      bfr[nf][0] = *(const bf16x8*)(ldsc + bAd0 + nf * 2048);
      bfr[nf][1] = *(const bf16x8*)(ldsc + bAd1 + nf * 2048);
    }

    // ---- 4 phases, no barriers: waves drift, LDS latency hides under
    //      sibling-wave MFMA ----
#pragma unroll
    for (int p = 0; p < 4; ++p) {
      bf16x8 af[2][2];
#pragma unroll
      for (int mf = 0; mf < 2; ++mf) {
        af[mf][0] = *(const bf16x8*)(ldsc + aAd0 + (p * 32 + mf * 16) * 128);
        af[mf][1] = *(const bf16x8*)(ldsc + aAd1 + (p * 32 + mf * 16) * 128);
      }
      __builtin_amdgcn_s_setprio(1);
#pragma unroll
      for (int mf = 0; mf < 2; ++mf)
#pragma unroll
        for (int nf = 0; nf < 5; ++nf)
#pragma unroll
          for (int kk = 0; kk < 2; ++kk)
            acc[p * 2 + mf][nf] = __builtin_amdgcn_mfma_f32_16x16x32_bf16(
                af[mf][kk], bfr[nf][kk], acc[p * 2 + mf][nf], 0, 0, 0);
      __builtin_amdgcn_s_setprio(0);
    }

    // ---- tile boundary: staging landed, all my reads drained, then sync ----
    asm volatile("s_waitcnt vmcnt(0) lgkmcnt(0)" ::: "memory");
    __builtin_amdgcn_s_barrier();

    aAd0 += bufd; aAd1 += bufd; bAd0 += bufd; bAd1 += bufd;
    bufd = -bufd;
  }

  // ---- epilogue: 5 gates for (row, j) all live in this lane ----
  const int j = j0 + wn * 16 + lc;
  float bi[5];
#pragma unroll
  for (int g = 0; g < 5; ++g) bi[g] = bias[g * HID + j];
#pragma unroll
  for (int m = 0; m < 8; ++m) {
#pragma unroll
    for (int r = 0; r < 4; ++r) {
      const int row = m0 + wm * 128 + m * 16 + khalf * 4 + r;
      const int off = row * HID + j;
      float iv  = sigf(acc[m][0][r] + bi[0]);
      float flv = sigf(acc[m][1][r] + bi[1]);
      float frv = sigf(acc[m][2][r] + bi[2]);
      float ov  = sigf(acc[m][3][r] + bi[3]);
      float uv  = tanhf(acc[m][4][r] + bi[4]);
      float cv  = iv * uv + flv * c_left[off] + frv * c_right[off];
      out[off] = ov * tanhf(cv);
      out[B_ROWS * HID + off] = cv;
    }
  }
}

// ---------- fp32 fallback (only if ws too small) ----------
__global__ void lstm_fallback(const float* __restrict__ x, const float* __restrict__ hl,
                              const float* __restrict__ hr, const float* __restrict__ cl,
                              const float* __restrict__ cr, const float* __restrict__ W,
                              const float* __restrict__ b, float* __restrict__ out) {
  int64_t idx = (int64_t)blockIdx.x * blockDim.x + threadIdx.x;
  if (idx >= (int64_t)B_ROWS * HID) return;
  int bi = (int)(idx >> 10);
  int j  = (int)(idx & 1023);
  float acc[5];
#pragma unroll
  for (int g = 0; g < 5; ++g) acc[g] = b[g * HID + j];
  const float* segs[3] = {x + (int64_t)bi * 1024, hl + (int64_t)bi * 1024,
                          hr + (int64_t)bi * 1024};
  for (int s = 0; s < 3; ++s) {
    const float4* v = (const float4*)segs[s];
    for (int k4 = 0; k4 < 256; ++k4) {
      float4 a = v[k4];
#pragma unroll
      for (int g = 0; g < 5; ++g) {
        const float4 wv = *(const float4*)(W + (int64_t)(g * HID + j) * KDIM + s * 1024 + k4 * 4);
        acc[g] += a.x * wv.x + a.y * wv.y + a.z * wv.z + a.w * wv.w;
      }
    }
  }
  float iv = sigf(acc[0]), fl = sigf(acc[1]), fr = sigf(acc[2]), ov = sigf(acc[3]);
  float uv = tanhf(acc[4]);
  float cv = iv * uv + fl * cl[idx] + fr * cr[idx];
  out[idx] = ov * tanhf(cv);
  out[(int64_t)B_ROWS * HID + idx] = cv;
}

// ---------- host ----------
extern "C" void kernel_launch(void* const* d_in, const int* in_sizes, int n_in,
                              void* d_out, int out_size, void* d_ws, size_t ws_size,
                              hipStream_t stream) {
  const float* x  = (const float*)d_in[0];
  const float* hl = (const float*)d_in[1];
  const float* cl = (const float*)d_in[2];
  const float* hr = (const float*)d_in[3];
  const float* cr = (const float*)d_in[4];
  const float* W  = (const float*)d_in[5];
  const float* b  = (const float*)d_in[6];
  float* out = (float*)d_out;

  const size_t needA = (size_t)B_ROWS * KDIM * sizeof(short);      // 48 MiB
  const size_t needW = (size_t)NGATE * HID * KDIM * sizeof(short); // 30 MiB

  if (ws_size >= needA + needW) {
    short* Abf = (short*)d_ws;
    short* Wbf = (short*)((char*)d_ws + needA);
    convert_combined<<<2048, 256, 0, stream>>>(x, hl, hr, Abf);
    convert_w<<<2048, 256, 0, stream>>>(W, Wbf);
    lstm_gemm<<<512, 512, 0, stream>>>(Abf, Wbf, b, cl, cr, out);
  } else {
    lstm_fallback<<<(B_ROWS * HID) / 256, 256, 0, stream>>>(x, hl, hr, cl, cr, W, b, out);
  }
}